// Round 1
// baseline (650.567 us; speedup 1.0000x reference)
//
#include <hip/hip_runtime.h>

// ---------------------------------------------------------------------------
// TFN forward. Pipeline:
//  k0: transpose encoder weights (for coalesced K1 reads)
//  k1: encoders -> a1T/v1T/t1T [97(98)][64] transposed, fp32 (row0 = ones)
//  k2: s[run][b] = a1T[i][b]*v1T[j][b] (run = i*97+j, padded to 9412 w/ zeros)
//      + t1pk[b][p] = packed bf16 pairs of t1 (zero-padded to 64 pairs)
//  k3: the big one: y1-partials = fusion @ W1 via bf16 MFMA, split-K over
//      589 wgs. W1 (350 MB) streamed once via global_load_lds; fusion frags
//      generated on the fly (q-lane-group = run, 8 elems = consecutive k).
//  k4: y1 = relu(sum partials + b1)
//  k5: features = relu(y1@W2+b2); 3 heads; interloss=0
// ---------------------------------------------------------------------------

typedef unsigned int u32;
typedef short frag8s __attribute__((ext_vector_type(8)));   // 8 bf16 in 4 VGPRs
typedef float f32x4 __attribute__((ext_vector_type(4)));

constexpr int G3     = 589;    // main kernel grid (4-run groups per wg: 4,4,...,3)
constexpr int NRUN   = 9409;   // 97*97 (i,j) runs
constexpr int NRUNP  = 9412;   // padded to multiple of 4 (pad runs have s=0)
constexpr int NGROUP = 2353;   // ceil(9409/4)

// workspace layout (float-element offsets)
constexpr int WS_A1T  = 0;                      // 98*64
constexpr int WS_V1T  = WS_A1T + 98 * 64;
constexpr int WS_T1T  = WS_V1T + 98 * 64;       // row 97 zeroed (pair padding)
constexpr int WS_T1PK = WS_T1T + 98 * 64;       // u32 64*64 (pairs 49..63 = 0)
constexpr int WS_S    = WS_T1PK + 64 * 64;      // 9412*64
constexpr int WS_WAT  = WS_S + NRUNP * 64;      // 96*512
constexpr int WS_WTT  = WS_WAT + 96 * 512;      // 96*1024
constexpr int WS_WVT  = WS_WTT + 96 * 1024;     // 96*512
constexpr int WS_Y1   = WS_WVT + 96 * 512;      // 6144
constexpr int WS_PART = WS_Y1 + 6144;           // G3*6144  (~14.5 MB)

__device__ __forceinline__ u32 bfrne(float x) {          // fp32 -> bf16 RNE
    u32 u = __float_as_uint(x);
    return (u + 0x7FFFu + ((u >> 16) & 1u)) >> 16;
}
__device__ __forceinline__ float bflo(u32 p) { return __uint_as_float(p << 16); }
__device__ __forceinline__ float bfhi(u32 p) { return __uint_as_float(p & 0xFFFF0000u); }

__device__ __forceinline__ void async_cp16(float* lds, const float* g) {
    __builtin_amdgcn_global_load_lds((const __attribute__((address_space(1))) u32*)g,
                                     (__attribute__((address_space(3))) u32*)lds, 16, 0, 0);
}
__device__ __forceinline__ void async_cp4(float* lds, const float* g) {
    __builtin_amdgcn_global_load_lds((const __attribute__((address_space(1))) u32*)g,
                                     (__attribute__((address_space(3))) u32*)lds, 4, 0, 0);
}

// ---------------- k0: weight transposes (tiny, 788 KB) ----------------
__global__ void k0_transpose(const float* __restrict__ Wa, const float* __restrict__ Wt,
                             const float* __restrict__ Wv, float* __restrict__ ws) {
    int idx = blockIdx.x * 256 + threadIdx.x;          // 196608 total
    if (idx < 49152) {
        int h = idx / 512, k = idx % 512;
        ws[WS_WAT + h * 512 + k] = Wa[k * 96 + h];
    } else if (idx < 147456) {
        int i = idx - 49152; int h = i / 1024, k = i % 1024;
        ws[WS_WTT + h * 1024 + k] = Wt[k * 96 + h];
    } else if (idx < 196608) {
        int i = idx - 147456; int h = i / 512, k = i % 512;
        ws[WS_WVT + h * 512 + k] = Wv[k * 96 + h];
    }
}

// ---------------- k1: encoders (wave-per-row dot + shfl reduce) ----------------
__global__ __launch_bounds__(256) void k1_enc(const float* __restrict__ audios,
                                              const float* __restrict__ texts,
                                              const float* __restrict__ videos,
                                              const float* __restrict__ ba,
                                              const float* __restrict__ bt,
                                              const float* __restrict__ bv,
                                              float* __restrict__ ws) {
    int wg = blockIdx.x, tid = threadIdx.x;
    int lane = tid & 63, wv = tid >> 6;
    if (wg == 288) {                      // zero t1T row 97 (pair padding)
        if (tid < 64) ws[WS_T1T + 97 * 64 + tid] = 0.0f;
        return;
    }
    int e = wg / 96, h = wg % 96;
    const float* in; const float* wt; float bias; int K; int outbase;
    if (e == 0)      { in = audios; wt = ws + WS_WAT + h * 512;  bias = ba[h]; K = 512;  outbase = WS_A1T; }
    else if (e == 1) { in = texts;  wt = ws + WS_WTT + h * 1024; bias = bt[h]; K = 1024; outbase = WS_T1T; }
    else             { in = videos; wt = ws + WS_WVT + h * 512;  bias = bv[h]; K = 512;  outbase = WS_V1T; }
    int nsweep = K >> 8;                  // 2 or 4 float4 sweeps per lane
    float4 wreg[4];
    for (int s = 0; s < nsweep; s++) wreg[s] = ((const float4*)wt)[s * 64 + lane];
    for (int pass = 0; pass < 16; pass++) {
        int b = pass * 4 + wv;
        float acc = 0.f;
        for (int s = 0; s < nsweep; s++) {
            float4 iv = ((const float4*)(in + b * K))[s * 64 + lane];
            acc += iv.x * wreg[s].x + iv.y * wreg[s].y + iv.z * wreg[s].z + iv.w * wreg[s].w;
        }
        for (int off = 32; off; off >>= 1) acc += __shfl_down(acc, off, 64);
        if (lane == 0) {
            float v = acc + bias;
            ws[outbase + (h + 1) * 64 + b] = v > 0.f ? v : 0.f;
        }
    }
    if (h == 0 && tid < 64) ws[outbase + tid] = 1.0f;   // leading-ones row
}

// ---------------- k2: s = a1 (x) v1 outer products + t1 bf16 pair packing ----------------
__global__ __launch_bounds__(256) void k2_s(float* __restrict__ ws) {
    int wg = blockIdx.x, tid = threadIdx.x;
    u32* t1pk = (u32*)ws + WS_T1PK;
    if (wg == 589) {                                  // pack t1 pairs
        for (int i = tid; i < 4096; i += 256) {
            int b = i >> 6, p = i & 63;
            u32 v = 0;
            if (p < 49) {                             // rows 0..97 (97 is zeros)
                float e0 = ws[WS_T1T + (2 * p) * 64 + b];
                float e1 = ws[WS_T1T + (2 * p + 1) * 64 + b];
                v = bfrne(e0) | (bfrne(e1) << 16);
            }
            t1pk[i] = v;
        }
        return;
    }
    for (int ii = 0; ii < 4; ii++) {
        int idx = wg * 1024 + ii * 256 + tid;
        if (idx >= NRUNP * 64) break;
        int run = idx >> 6, b = idx & 63;
        float s = 0.f;
        if (run < NRUN) {
            int i = run / 97, j = run % 97;
            s = ws[WS_A1T + i * 64 + b] * ws[WS_V1T + j * 64 + b];
        }
        ws[WS_S + idx] = s;
    }
}

// ---------------- k3: the 350 MB streaming MFMA kernel ----------------
// Per wg: 256 thr = 4 waves. Wave w owns batch rows [16w,16w+16) x all 96 h
// (6 N-tiles of 16x16x32 MFMA, 24 acc regs). K-step = 32 = 4 runs x 8 k:
// MFMA k-group q = lane>>4 selects run (group*4+q), elems j = consecutive k.
// W1 tile (4 runs x 8 rows x 96 fp32 = 12 KB) double-buffered via
// global_load_lds; fp32->bf16 by truncation at B-frag build (error << thr).
__global__ __launch_bounds__(256) void k3_main(const float* __restrict__ W1,
                                               float* __restrict__ ws) {
    __shared__ float wtile[2][32 * 96];     // 24576 B
    __shared__ u32   tpk[64 * 65];          // 16640 B (pad 65 for banks)
    __shared__ float sl[2][4 * 64];         // 2048 B

    int tid = threadIdx.x, lane = tid & 63, wv = tid >> 6;
    int id = blockIdx.x;
    const u32* t1pk_g = (const u32*)ws + WS_T1PK;
    const float* s_g = ws + WS_S;

    // safety: make both W buffers finite before first use
    for (int i = tid; i < 2 * 32 * 96 / 4; i += 256)
        ((float4*)wtile)[i] = make_float4(0.f, 0.f, 0.f, 0.f);
    // stage t1 pairs (padded stride 65 -> conflict-free reads)
    for (int i = tid; i < 4096; i += 256) {
        int b = i >> 6, p = i & 63;
        tpk[b * 65 + p] = t1pk_g[i];
    }

    int glist[4]; int gcount = 0;
    for (int i2 = 0; i2 < 4; i2++) { int g = id + i2 * G3; if (g < NGROUP) glist[gcount++] = g; }

    f32x4 acc[6];
    for (int nt = 0; nt < 6; nt++) acc[nt] = f32x4{0.f, 0.f, 0.f, 0.f};

    auto stage_w = [&](int g, int koff, int buf) {
        int run = g * 4 + wv; if (run > 9408) run = 9408;   // clamp pad runs (s=0 kills them)
        if (koff < 96) {
            const float* gsrc = W1 + (size_t)(run * 97 + koff) * 96;
            float* ldst = &wtile[buf][wv * 768];
            for (int c = 0; c < 3; c++)
                async_cp16(ldst + c * 256, gsrc + c * 256 + lane * 4);
        } else {                                            // tail: only k=96 row
            if (lane < 24)
                async_cp16(&wtile[buf][wv * 768], W1 + (size_t)(run * 97 + 96) * 96 + lane * 4);
        }
    };
    auto stage_s = [&](int g, int sb) {
        if (wv == 0) {
            for (int q2 = 0; q2 < 4; q2++) {
                int run = g * 4 + q2;                       // <= 9411 < 9412, zero-padded
                async_cp4(&sl[sb][q2 * 64], s_g + run * 64 + lane);
            }
        }
    };

    stage_s(glist[0], 0);
    stage_w(glist[0], 0, 0);
    __syncthreads();    // drains vmcnt -> staged data visible

    int pw = 0, sb = 0;
    int b = (wv << 4) + (lane & 15);      // A-frag row -> batch
    int q = lane >> 4;                    // k-group -> run select

    for (int gi = 0; gi < gcount; gi++) {
        int g = glist[gi];
        for (int step = 0; step < 13; step++) {
            int koff = step * 8;
            // prefetch next tile (and next group's s at group end)
            if (step < 12) stage_w(g, koff + 8, pw ^ 1);
            else if (gi + 1 < gcount) { stage_w(glist[gi + 1], 0, pw ^ 1); stage_s(glist[gi + 1], sb ^ 1); }

            // A-frag: f[b, k] = s_run[b] * t1[b, koff+j]  (RNE-packed bf16 pairs)
            float s = sl[sb][q * 64 + b];
            int pb = b * 65 + (koff >> 1);
            u32 ap[4];
#pragma unroll
            for (int r = 0; r < 4; r++) {
                u32 tp = tpk[pb + r];
                float fe = s * bflo(tp), fo = s * bfhi(tp);
                ap[r] = bfrne(fe) | (bfrne(fo) << 16);
            }
            union { u32 u[4]; frag8s f; } afr;
            afr.u[0] = ap[0]; afr.u[1] = ap[1]; afr.u[2] = ap[2]; afr.u[3] = ap[3];

            const float* wt0 = &wtile[pw][q * 768 + (lane & 15)];
#pragma unroll
            for (int nt = 0; nt < 6; nt++) {
                union { u32 u[4]; frag8s f; } bfr;
#pragma unroll
                for (int r = 0; r < 4; r++) {
                    u32 w0 = __float_as_uint(wt0[(2 * r) * 96 + nt * 16]);
                    u32 w1 = __float_as_uint(wt0[(2 * r + 1) * 96 + nt * 16]);
                    bfr.u[r] = (w0 >> 16) | (w1 & 0xFFFF0000u);   // bf16 truncate-pack
                }
                acc[nt] = __builtin_amdgcn_mfma_f32_16x16x32_bf16(afr.f, bfr.f, acc[nt], 0, 0, 0);
            }
            __syncthreads();
            pw ^= 1;
        }
        sb ^= 1;
    }

    // write 64x96 fp32 partial (C layout: col=lane&15, row=(lane>>4)*4+r)
    float* part = ws + WS_PART + (size_t)id * 6144;
#pragma unroll
    for (int nt = 0; nt < 6; nt++) {
#pragma unroll
        for (int r = 0; r < 4; r++) {
            int row = (wv << 4) + ((lane >> 4) << 2) + r;
            int col = nt * 16 + (lane & 15);
            part[row * 96 + col] = acc[nt][r];
        }
    }
}

// ---------------- k4: reduce partials -> y1 = relu(. + b1) ----------------
__global__ __launch_bounds__(256) void k4_reduce(const float* __restrict__ b1,
                                                 float* __restrict__ ws) {
    int o = blockIdx.x * 256 + threadIdx.x;    // 6144
    const float* part = ws + WS_PART + o;
    float a0 = 0.f, a1 = 0.f, a2 = 0.f, a3 = 0.f;
    int w = 0;
    for (; w + 4 <= G3; w += 4) {
        a0 += part[(size_t)(w + 0) * 6144];
        a1 += part[(size_t)(w + 1) * 6144];
        a2 += part[(size_t)(w + 2) * 6144];
        a3 += part[(size_t)(w + 3) * 6144];
    }
    for (; w < G3; w++) a0 += part[(size_t)w * 6144];
    float acc = (a0 + a1) + (a2 + a3) + b1[o % 96];
    ws[WS_Y1 + o] = acc > 0.f ? acc : 0.f;
}

// ---------------- k5: features + heads (single wg, ~1.3 MFLOP) ----------------
__global__ __launch_bounds__(256) void k5_final(const float* __restrict__ W2, const float* __restrict__ b2,
                                                const float* __restrict__ Wo1, const float* __restrict__ bo1,
                                                const float* __restrict__ Wo2, const float* __restrict__ bo2,
                                                const float* __restrict__ Wo3, const float* __restrict__ bo3,
                                                const float* __restrict__ ws, float* __restrict__ out) {
    __shared__ float yl[64 * 96];
    __shared__ float w2l[96 * 97];     // +1 pad
    __shared__ float fl[64 * 96];
    int tid = threadIdx.x;
    for (int i = tid; i < 6144; i += 256) yl[i] = ws[WS_Y1 + i];
    for (int i = tid; i < 9216; i += 256) { int k = i / 96, h = i % 96; w2l[k * 97 + h] = W2[i]; }
    __syncthreads();
    for (int i = tid; i < 6144; i += 256) {
        int bb = i / 96, h = i % 96;
        float acc = b2[h];
#pragma unroll 8
        for (int k = 0; k < 96; k++) acc += yl[bb * 96 + k] * w2l[k * 97 + h];
        float f = acc > 0.f ? acc : 0.f;
        fl[i] = f; out[i] = f;
    }
    __syncthreads();
    for (int i = tid; i < 640; i += 256) {
        if (i < 384) {
            int bb = i / 6, j = i % 6;
            float acc = bo1[j];
            for (int k = 0; k < 96; k++) acc += fl[bb * 96 + k] * Wo1[k * 6 + j];
            out[6144 + i] = acc;
        } else if (i < 448) {
            int bb = i - 384;
            float acc = bo2[0];
            for (int k = 0; k < 96; k++) acc += fl[bb * 96 + k] * Wo2[k];
            out[6144 + i] = acc;
        } else {
            int t2 = i - 448; int bb = t2 / 3, j = t2 % 3;
            float acc = bo3[j];
            for (int k = 0; k < 96; k++) acc += fl[bb * 96 + k] * Wo3[k * 3 + j];
            out[6144 + i] = acc;
        }
    }
    if (tid == 0) out[6784] = 0.0f;    // interloss
}

extern "C" void kernel_launch(void* const* d_in, const int* in_sizes, int n_in,
                              void* d_out, int out_size, void* d_ws, size_t ws_size,
                              hipStream_t stream) {
    (void)in_sizes; (void)n_in; (void)out_size; (void)ws_size;
    const float* audios = (const float*)d_in[0];
    const float* texts  = (const float*)d_in[1];
    const float* videos = (const float*)d_in[2];
    const float* Wa  = (const float*)d_in[3];
    const float* ba  = (const float*)d_in[4];
    const float* Wt  = (const float*)d_in[5];
    const float* bt  = (const float*)d_in[6];
    const float* Wv  = (const float*)d_in[7];
    const float* bv  = (const float*)d_in[8];
    const float* W1  = (const float*)d_in[9];
    const float* b1  = (const float*)d_in[10];
    const float* W2  = (const float*)d_in[11];
    const float* b2  = (const float*)d_in[12];
    const float* Wo1 = (const float*)d_in[13];
    const float* bo1 = (const float*)d_in[14];
    const float* Wo2 = (const float*)d_in[15];
    const float* bo2 = (const float*)d_in[16];
    const float* Wo3 = (const float*)d_in[17];
    const float* bo3 = (const float*)d_in[18];
    float* ws = (float*)d_ws;
    float* outp = (float*)d_out;

    k0_transpose<<<768, 256, 0, stream>>>(Wa, Wt, Wv, ws);
    k1_enc<<<289, 256, 0, stream>>>(audios, texts, videos, ba, bt, bv, ws);
    k2_s<<<590, 256, 0, stream>>>(ws);
    k3_main<<<G3, 256, 0, stream>>>(W1, ws);
    k4_reduce<<<24, 256, 0, stream>>>(b1, ws);
    k5_final<<<1, 256, 0, stream>>>(W2, b2, Wo1, bo1, Wo2, bo2, Wo3, bo3, ws, outp);
}

// Round 2
// 595.173 us; speedup vs baseline: 1.0931x; 1.0931x over previous
//
#include <hip/hip_runtime.h>

// ---------------------------------------------------------------------------
// TFN forward. Pipeline:
//  k0: transpose encoder weights (for coalesced K1 reads)
//  k1: encoders -> a1T/v1T/t1T [97(98)][64] transposed, fp32 (row0 = ones)
//  k2: s[run][b] = a1T[i][b]*v1T[j][b] (run = i*97+j, padded to 9412 w/ zeros)
//      + t1pk[b][p] = packed bf16 pairs of t1 (zero-padded to 64 pairs)
//  k3: y1-partials = fusion @ W1 via bf16 MFMA, split-K over 589 wgs.
//      W1 (350 MB) streamed once via global_load_lds; fusion frags generated
//      on the fly. LDS run-block stride 776 (776%32=8) -> B-frag reads are
//      2-way/bank = conflict-free (768 stride was 4-way conflicted).
//  k4a: 192 wgs, each sums a 74-partial chunk -> PART2[8][6144]
//  k5: 8 wgs: y1 = relu(sum8+b1); features = relu(y1@W2+b2); heads; interloss
// ---------------------------------------------------------------------------

typedef unsigned int u32;
typedef short frag8s __attribute__((ext_vector_type(8)));   // 8 bf16 in 4 VGPRs
typedef float f32x4 __attribute__((ext_vector_type(4)));

constexpr int G3     = 589;    // main kernel grid
constexpr int NRUN   = 9409;   // 97*97 (i,j) runs
constexpr int NRUNP  = 9412;   // padded to multiple of 4 (pad runs have s=0)
constexpr int NGROUP = 2353;   // ceil(9409/4)
constexpr int RBLK   = 776;    // LDS floats per run-block (768 used + 8 pad)

// workspace layout (float-element offsets)
constexpr int WS_A1T  = 0;                      // 98*64
constexpr int WS_V1T  = WS_A1T + 98 * 64;
constexpr int WS_T1T  = WS_V1T + 98 * 64;       // row 97 zeroed (pair padding)
constexpr int WS_T1PK = WS_T1T + 98 * 64;       // u32 64*64 (pairs 49..63 = 0)
constexpr int WS_S    = WS_T1PK + 64 * 64;      // 9412*64
constexpr int WS_WAT  = WS_S + NRUNP * 64;      // 96*512
constexpr int WS_WTT  = WS_WAT + 96 * 512;      // 96*1024
constexpr int WS_WVT  = WS_WTT + 96 * 1024;     // 96*512
constexpr int WS_PART = WS_WVT + 96 * 512;      // G3*6144  (~14.5 MB)
constexpr int WS_PART2= WS_PART + G3 * 6144;    // 8*6144

__device__ __forceinline__ u32 bfrne(float x) {          // fp32 -> bf16 RNE
    u32 u = __float_as_uint(x);
    return (u + 0x7FFFu + ((u >> 16) & 1u)) >> 16;
}
__device__ __forceinline__ float bflo(u32 p) { return __uint_as_float(p << 16); }
__device__ __forceinline__ float bfhi(u32 p) { return __uint_as_float(p & 0xFFFF0000u); }

__device__ __forceinline__ void async_cp16(float* lds, const float* g) {
    __builtin_amdgcn_global_load_lds((const __attribute__((address_space(1))) u32*)g,
                                     (__attribute__((address_space(3))) u32*)lds, 16, 0, 0);
}
__device__ __forceinline__ void async_cp4(float* lds, const float* g) {
    __builtin_amdgcn_global_load_lds((const __attribute__((address_space(1))) u32*)g,
                                     (__attribute__((address_space(3))) u32*)lds, 4, 0, 0);
}

// ---------------- k0: weight transposes (tiny, 788 KB) ----------------
__global__ void k0_transpose(const float* __restrict__ Wa, const float* __restrict__ Wt,
                             const float* __restrict__ Wv, float* __restrict__ ws) {
    int idx = blockIdx.x * 256 + threadIdx.x;          // 196608 total
    if (idx < 49152) {
        int h = idx / 512, k = idx % 512;
        ws[WS_WAT + h * 512 + k] = Wa[k * 96 + h];
    } else if (idx < 147456) {
        int i = idx - 49152; int h = i / 1024, k = i % 1024;
        ws[WS_WTT + h * 1024 + k] = Wt[k * 96 + h];
    } else if (idx < 196608) {
        int i = idx - 147456; int h = i / 512, k = i % 512;
        ws[WS_WVT + h * 512 + k] = Wv[k * 96 + h];
    }
}

// ---------------- k1: encoders (wave-per-row dot + shfl reduce) ----------------
__global__ __launch_bounds__(256) void k1_enc(const float* __restrict__ audios,
                                              const float* __restrict__ texts,
                                              const float* __restrict__ videos,
                                              const float* __restrict__ ba,
                                              const float* __restrict__ bt,
                                              const float* __restrict__ bv,
                                              float* __restrict__ ws) {
    int wg = blockIdx.x, tid = threadIdx.x;
    int lane = tid & 63, wv = tid >> 6;
    if (wg == 288) {                      // zero t1T row 97 (pair padding)
        if (tid < 64) ws[WS_T1T + 97 * 64 + tid] = 0.0f;
        return;
    }
    int e = wg / 96, h = wg % 96;
    const float* in; const float* wt; float bias; int K; int outbase;
    if (e == 0)      { in = audios; wt = ws + WS_WAT + h * 512;  bias = ba[h]; K = 512;  outbase = WS_A1T; }
    else if (e == 1) { in = texts;  wt = ws + WS_WTT + h * 1024; bias = bt[h]; K = 1024; outbase = WS_T1T; }
    else             { in = videos; wt = ws + WS_WVT + h * 512;  bias = bv[h]; K = 512;  outbase = WS_V1T; }
    int nsweep = K >> 8;                  // 2 or 4 float4 sweeps per lane
    float4 wreg[4];
    for (int s = 0; s < nsweep; s++) wreg[s] = ((const float4*)wt)[s * 64 + lane];
    for (int pass = 0; pass < 16; pass++) {
        int b = pass * 4 + wv;
        float acc = 0.f;
        for (int s = 0; s < nsweep; s++) {
            float4 iv = ((const float4*)(in + b * K))[s * 64 + lane];
            acc += iv.x * wreg[s].x + iv.y * wreg[s].y + iv.z * wreg[s].z + iv.w * wreg[s].w;
        }
        for (int off = 32; off; off >>= 1) acc += __shfl_down(acc, off, 64);
        if (lane == 0) {
            float v = acc + bias;
            ws[outbase + (h + 1) * 64 + b] = v > 0.f ? v : 0.f;
        }
    }
    if (h == 0 && tid < 64) ws[outbase + tid] = 1.0f;   // leading-ones row
}

// ---------------- k2: s = a1 (x) v1 outer products + t1 bf16 pair packing ----------------
__global__ __launch_bounds__(256) void k2_s(float* __restrict__ ws) {
    int wg = blockIdx.x, tid = threadIdx.x;
    u32* t1pk = (u32*)ws + WS_T1PK;
    if (wg == 589) {                                  // pack t1 pairs
        for (int i = tid; i < 4096; i += 256) {
            int b = i >> 6, p = i & 63;
            u32 v = 0;
            if (p < 49) {                             // rows 0..97 (97 is zeros)
                float e0 = ws[WS_T1T + (2 * p) * 64 + b];
                float e1 = ws[WS_T1T + (2 * p + 1) * 64 + b];
                v = bfrne(e0) | (bfrne(e1) << 16);
            }
            t1pk[i] = v;
        }
        return;
    }
    for (int ii = 0; ii < 4; ii++) {
        int idx = wg * 1024 + ii * 256 + tid;
        if (idx >= NRUNP * 64) break;
        int run = idx >> 6, b = idx & 6 * 10 + 3;     // b = idx & 63
        b = idx & 63;
        float s = 0.f;
        if (run < NRUN) {
            int i = run / 97, j = run % 97;
            s = ws[WS_A1T + i * 64 + b] * ws[WS_V1T + j * 64 + b];
        }
        ws[WS_S + idx] = s;
    }
}

// ---------------- k3: the 350 MB streaming MFMA kernel ----------------
// Per wg: 4 waves. Wave w owns batch rows [16w,16w+16) x all 96 h (6 N-tiles
// of 16x16x32 MFMA). K-step = 32 = 4 runs x 8 k: MFMA k-group q = lane>>4
// selects run, elems j = consecutive k. W1 tile (4 runs x 8 rows x 96 fp32)
// double-buffered via global_load_lds. Run-block LDS stride RBLK=776
// (776%32=8): B-frag reads hit banks (lane&15)+8q -> 2/bank = free.
__global__ __launch_bounds__(256) void k3_main(const float* __restrict__ W1,
                                               float* __restrict__ ws) {
    __shared__ float wtile[2][4 * RBLK];    // 24832 B
    __shared__ u32   tpk[64 * 65];          // 16640 B (pad 65 for banks)
    __shared__ float sl[2][4 * 64];         // 2048 B

    int tid = threadIdx.x, lane = tid & 63, wv = tid >> 6;
    int id = blockIdx.x;
    const u32* t1pk_g = (const u32*)ws + WS_T1PK;
    const float* s_g = ws + WS_S;

    // safety: make both W buffers finite before first use
    for (int i = tid; i < 2 * 4 * RBLK / 4; i += 256)
        ((float4*)wtile)[i] = make_float4(0.f, 0.f, 0.f, 0.f);
    // stage t1 pairs (padded stride 65 -> broadcast/conflict-free reads)
    for (int i = tid; i < 4096; i += 256) {
        int b = i >> 6, p = i & 63;
        tpk[b * 65 + p] = t1pk_g[i];
    }

    int glist[4]; int gcount = 0;
    for (int i2 = 0; i2 < 4; i2++) { int g = id + i2 * G3; if (g < NGROUP) glist[gcount++] = g; }

    f32x4 acc[6];
    for (int nt = 0; nt < 6; nt++) acc[nt] = f32x4{0.f, 0.f, 0.f, 0.f};

    auto stage_w = [&](int g, int koff, int buf) {
        int run = g * 4 + wv; if (run > 9408) run = 9408;   // clamp pad runs (s=0 kills them)
        if (koff < 96) {
            const float* gsrc = W1 + (size_t)(run * 97 + koff) * 96;
            float* ldst = &wtile[buf][wv * RBLK];
            for (int c = 0; c < 3; c++)
                async_cp16(ldst + c * 256, gsrc + c * 256 + lane * 4);
        } else {                                            // tail: only k=96 row
            if (lane < 24)
                async_cp16(&wtile[buf][wv * RBLK], W1 + (size_t)(run * 97 + 96) * 96 + lane * 4);
        }
    };
    auto stage_s = [&](int g, int sb) {
        if (wv == 0) {
            for (int q2 = 0; q2 < 4; q2++) {
                int run = g * 4 + q2;                       // <= 9411 < 9412, zero-padded
                async_cp4(&sl[sb][q2 * 64], s_g + run * 64 + lane);
            }
        }
    };

    stage_s(glist[0], 0);
    stage_w(glist[0], 0, 0);
    __syncthreads();    // drains vmcnt -> staged data visible

    int pw = 0, sb = 0;
    int b = (wv << 4) + (lane & 15);      // A-frag row -> batch
    int q = lane >> 4;                    // k-group -> run select

    for (int gi = 0; gi < gcount; gi++) {
        int g = glist[gi];
        for (int step = 0; step < 13; step++) {
            int koff = step * 8;
            // prefetch next tile (and next group's s at group end)
            if (step < 12) stage_w(g, koff + 8, pw ^ 1);
            else if (gi + 1 < gcount) { stage_w(glist[gi + 1], 0, pw ^ 1); stage_s(glist[gi + 1], sb ^ 1); }

            // A-frag: f[b, k] = s_run[b] * t1[b, koff+j]  (RNE-packed bf16 pairs)
            float s = sl[sb][q * 64 + b];
            int pb = b * 65 + (koff >> 1);
            u32 ap[4];
#pragma unroll
            for (int r = 0; r < 4; r++) {
                u32 tp = tpk[pb + r];
                float fe = s * bflo(tp), fo = s * bfhi(tp);
                ap[r] = bfrne(fe) | (bfrne(fo) << 16);
            }
            union { u32 u[4]; frag8s f; } afr;
            afr.u[0] = ap[0]; afr.u[1] = ap[1]; afr.u[2] = ap[2]; afr.u[3] = ap[3];

            const float* wt0 = &wtile[pw][q * RBLK + (lane & 15)];
#pragma unroll
            for (int nt = 0; nt < 6; nt++) {
                union { u32 u[4]; frag8s f; } bfr;
#pragma unroll
                for (int r = 0; r < 4; r++) {
                    u32 w0 = __float_as_uint(wt0[(2 * r) * 96 + nt * 16]);
                    u32 w1 = __float_as_uint(wt0[(2 * r + 1) * 96 + nt * 16]);
                    bfr.u[r] = (w0 >> 16) | (w1 & 0xFFFF0000u);   // bf16 truncate-pack
                }
                acc[nt] = __builtin_amdgcn_mfma_f32_16x16x32_bf16(afr.f, bfr.f, acc[nt], 0, 0, 0);
            }
            __syncthreads();
            pw ^= 1;
        }
        sb ^= 1;
    }

    // write 64x96 fp32 partial (C layout: col=lane&15, row=(lane>>4)*4+r)
    float* part = ws + WS_PART + (size_t)id * 6144;
#pragma unroll
    for (int nt = 0; nt < 6; nt++) {
#pragma unroll
        for (int r = 0; r < 4; r++) {
            int row = (wv << 4) + ((lane >> 4) << 2) + r;
            int col = nt * 16 + (lane & 15);
            part[row * 96 + col] = acc[nt][r];
        }
    }
}

// ---------------- k4a: partial-sum stage A (192 wgs, 8 chunks of <=74) ----------------
__global__ __launch_bounds__(256) void k4a_reduce(float* __restrict__ ws) {
    int bid = blockIdx.x;
    int oc = bid % 24, wc = bid / 24;          // wc in [0,8)
    int o = oc * 256 + threadIdx.x;            // output index in [0,6144)
    int w0 = wc * 74, w1 = w0 + 74; if (w1 > G3) w1 = G3;
    const float* part = ws + WS_PART + o;
    float a0 = 0.f, a1 = 0.f;
    int w = w0;
    for (; w + 2 <= w1; w += 2) {
        a0 += part[(size_t)w * 6144];
        a1 += part[(size_t)(w + 1) * 6144];
    }
    for (; w < w1; w++) a0 += part[(size_t)w * 6144];
    ws[WS_PART2 + (size_t)wc * 6144 + o] = a0 + a1;
}

// ---------------- k5: y1 finalize + features + heads (8 wgs, 8 rows each) ----------------
__global__ __launch_bounds__(256) void k5_final(const float* __restrict__ b1,
                                                const float* __restrict__ W2, const float* __restrict__ b2,
                                                const float* __restrict__ Wo1, const float* __restrict__ bo1,
                                                const float* __restrict__ Wo2, const float* __restrict__ bo2,
                                                const float* __restrict__ Wo3, const float* __restrict__ bo3,
                                                const float* __restrict__ ws, float* __restrict__ out) {
    __shared__ float yl[8 * 96];
    __shared__ float w2l[96 * 97];     // +1 pad
    __shared__ float fl[8 * 96];
    int tid = threadIdx.x;
    int row0 = blockIdx.x * 8;
    // y1 rows [row0, row0+8): 8-way partial sum + bias + relu
    for (int i = tid; i < 768; i += 256) {
        int go = row0 * 96 + i;
        float acc = b1[i % 96];
#pragma unroll
        for (int w = 0; w < 8; w++) acc += ws[WS_PART2 + (size_t)w * 6144 + go];
        yl[i] = acc > 0.f ? acc : 0.f;
    }
    for (int i = tid; i < 9216; i += 256) { int k = i / 96, h = i % 96; w2l[k * 97 + h] = W2[i]; }
    __syncthreads();
    for (int i = tid; i < 768; i += 256) {
        int bb = i / 96, h = i % 96;
        float acc = b2[h];
#pragma unroll 8
        for (int k = 0; k < 96; k++) acc += yl[bb * 96 + k] * w2l[k * 97 + h];
        float f = acc > 0.f ? acc : 0.f;
        fl[i] = f; out[(row0 + bb) * 96 + h] = f;
    }
    __syncthreads();
    // heads for rows [row0, row0+8): 48 + 8 + 24 = 80 outputs
    if (tid < 80) {
        if (tid < 48) {
            int lr = tid / 6, j = tid % 6;
            float acc = bo1[j];
            for (int k = 0; k < 96; k++) acc += fl[lr * 96 + k] * Wo1[k * 6 + j];
            out[6144 + (row0 + lr) * 6 + j] = acc;
        } else if (tid < 56) {
            int lr = tid - 48;
            float acc = bo2[0];
            for (int k = 0; k < 96; k++) acc += fl[lr * 96 + k] * Wo2[k];
            out[6528 + row0 + lr] = acc;
        } else {
            int t2 = tid - 56; int lr = t2 / 3, j = t2 % 3;
            float acc = bo3[j];
            for (int k = 0; k < 96; k++) acc += fl[lr * 96 + k] * Wo3[k * 3 + j];
            out[6592 + (row0 + lr) * 3 + j] = acc;
        }
    }
    if (blockIdx.x == 0 && tid == 0) out[6784] = 0.0f;    // interloss
}

extern "C" void kernel_launch(void* const* d_in, const int* in_sizes, int n_in,
                              void* d_out, int out_size, void* d_ws, size_t ws_size,
                              hipStream_t stream) {
    (void)in_sizes; (void)n_in; (void)out_size; (void)ws_size;
    const float* audios = (const float*)d_in[0];
    const float* texts  = (const float*)d_in[1];
    const float* videos = (const float*)d_in[2];
    const float* Wa  = (const float*)d_in[3];
    const float* ba  = (const float*)d_in[4];
    const float* Wt  = (const float*)d_in[5];
    const float* bt  = (const float*)d_in[6];
    const float* Wv  = (const float*)d_in[7];
    const float* bv  = (const float*)d_in[8];
    const float* W1  = (const float*)d_in[9];
    const float* b1  = (const float*)d_in[10];
    const float* W2  = (const float*)d_in[11];
    const float* b2  = (const float*)d_in[12];
    const float* Wo1 = (const float*)d_in[13];
    const float* bo1 = (const float*)d_in[14];
    const float* Wo2 = (const float*)d_in[15];
    const float* bo2 = (const float*)d_in[16];
    const float* Wo3 = (const float*)d_in[17];
    const float* bo3 = (const float*)d_in[18];
    float* ws = (float*)d_ws;
    float* outp = (float*)d_out;

    k0_transpose<<<768, 256, 0, stream>>>(Wa, Wt, Wv, ws);
    k1_enc<<<289, 256, 0, stream>>>(audios, texts, videos, ba, bt, bv, ws);
    k2_s<<<590, 256, 0, stream>>>(ws);
    k3_main<<<G3, 256, 0, stream>>>(W1, ws);
    k4a_reduce<<<192, 256, 0, stream>>>(ws);
    k5_final<<<8, 256, 0, stream>>>(b1, W2, b2, Wo1, bo1, Wo2, bo2, Wo3, bo3, ws, outp);
}